// Round 3
// baseline (372.259 us; speedup 1.0000x reference)
//
#include <hip/hip_runtime.h>

#define B_   2
#define N_   2048
#define C_   1024
#define H_   16
#define D_   64
#define HID_ 4096
#define M_   (B_ * N_)   // 4096 rows

typedef __attribute__((ext_vector_type(8))) short bf16x8;  // 8 bf16 = 4 VGPRs
typedef __attribute__((ext_vector_type(4))) float f32x4;

__device__ __forceinline__ unsigned short f2bf(float f) {
  unsigned int u = __builtin_bit_cast(unsigned int, f);
  u += 0x7fffu + ((u >> 16) & 1u);   // RNE
  return (unsigned short)(u >> 16);
}

// pack 2 fp32 -> 2 bf16 (RNE), single instruction
__device__ __forceinline__ unsigned int cvtpk(float a, float b) {
  unsigned int r;
  asm("v_cvt_pk_bf16_f32 %0, %1, %2" : "=v"(r) : "v"(a), "v"(b));
  return r;
}

__device__ __forceinline__ float exp2a(float x) {
  float r;
  asm("v_exp_f32 %0, %1" : "=v"(r) : "v"(x));
  return r;
}

// async global->LDS, 16B per lane; LDS dest = wave-uniform base + lane*16
__device__ __forceinline__ void gl2lds16(const void* g, void* l) {
  __builtin_amdgcn_global_load_lds(
      (const __attribute__((address_space(1))) unsigned int*)g,
      (__attribute__((address_space(3))) unsigned int*)l, 16, 0, 0);
}

#define LOG2E 1.44269504088896f

// ---------------- LayerNorm (fp32 in -> bf16 out), one WAVE per row ----------------
__global__ __launch_bounds__(256) void ln_kernel(const float* __restrict__ x,
                                                 const float* __restrict__ g,
                                                 const float* __restrict__ bta,
                                                 unsigned short* __restrict__ out) {
  int row  = blockIdx.x * 4 + (threadIdx.x >> 6);
  int lane = threadIdx.x & 63;
  const float* xr = x + (size_t)row * C_;
  float4 v[4];
  float s1 = 0.f, s2 = 0.f;
#pragma unroll
  for (int j = 0; j < 4; j++) {
    v[j] = *(const float4*)(xr + j * 256 + lane * 4);
    s1 += v[j].x + v[j].y + v[j].z + v[j].w;
    s2 += v[j].x * v[j].x + v[j].y * v[j].y + v[j].z * v[j].z + v[j].w * v[j].w;
  }
#pragma unroll
  for (int m = 1; m < 64; m <<= 1) { s1 += __shfl_xor(s1, m); s2 += __shfl_xor(s2, m); }
  float mu  = s1 * (1.0f / C_);
  float var = s2 * (1.0f / C_) - mu * mu;
  float rs  = rsqrtf(var + 1e-5f);
#pragma unroll
  for (int j = 0; j < 4; j++) {
    const float4 gv = *(const float4*)(g + j * 256 + lane * 4);
    const float4 bv = *(const float4*)(bta + j * 256 + lane * 4);
    ushort4 o;
    o.x = f2bf((v[j].x - mu) * rs * gv.x + bv.x);
    o.y = f2bf((v[j].y - mu) * rs * gv.y + bv.y);
    o.z = f2bf((v[j].z - mu) * rs * gv.z + bv.z);
    o.w = f2bf((v[j].w - mu) * rs * gv.w + bv.w);
    *(ushort4*)(out + (size_t)row * C_ + j * 256 + lane * 4) = o;
  }
}

// ------------- All 4 weight transposes (fp32->bf16, W[K][N]->Wt[N][K]) in ONE dispatch
__global__ __launch_bounds__(256) void wtrans_all(
    const float* __restrict__ w0, const float* __restrict__ w1,
    const float* __restrict__ w2, const float* __restrict__ w3,
    unsigned short* __restrict__ o0, unsigned short* __restrict__ o1,
    unsigned short* __restrict__ o2, unsigned short* __restrict__ o3) {
  int id = blockIdx.x;
  const float* W; unsigned short* Wt; int K, N, rel;
  if (id < 3072)      { W = w0; Wt = o0; K = 1024; N = 3072; rel = id; }
  else if (id < 4096) { W = w1; Wt = o1; K = 1024; N = 1024; rel = id - 3072; }
  else if (id < 8192) { W = w2; Wt = o2; K = 1024; N = 4096; rel = id - 4096; }
  else                { W = w3; Wt = o3; K = 4096; N = 1024; rel = id - 8192; }
  int nx = N >> 5;
  int n0 = (rel % nx) * 32, k0 = (rel / nx) * 32;
  __shared__ float t[32][33];
  int tx = threadIdx.x, ty = threadIdx.y;  // 32 x 8
#pragma unroll
  for (int j = 0; j < 4; j++)
    t[ty + j * 8][tx] = W[(size_t)(k0 + ty + j * 8) * N + n0 + tx];
  __syncthreads();
#pragma unroll
  for (int j = 0; j < 4; j++)
    Wt[(size_t)(n0 + ty + j * 8) * K + k0 + tx] = f2bf(t[tx][ty + j * 8]);
}

// ---------------- bf16 MFMA GEMM (m97 2-barrier structure, proj / fc2) --------------
// BN=128: 4 waves 2x2 (64x64 each) -> 16 MFMA/K-step/wave, 256 blocks = 1/CU.
// T1 XCD swizzle: each XCD owns a contiguous chunk of M-blocks (A slice L2-resident).
// MODE 1: outf = acc + bias + resid (fp32)
template <int MODE, int BN>
__global__ __launch_bounds__(256) void gemm_kernel(
    const unsigned short* __restrict__ A,    // [M][K] bf16
    const unsigned short* __restrict__ Wt,   // [N][K] bf16
    const float* __restrict__ bias,
    const float* __restrict__ resid,
    float* __restrict__ outf,
    unsigned short* __restrict__ outb0,
    int M, int N, int K) {
  constexpr int MT = (BN == 128) ? 4 : 2;
  __shared__ __align__(16) short As[128][64];
  __shared__ __align__(16) short Bs[BN][64];
  int tid = threadIdx.x;
  int w = tid >> 6, lane = tid & 63, r = lane & 15, quad = lane >> 4;
  int rowbase = (BN == 128) ? (w >> 1) * 64 : w * 32;
  int colbase = (BN == 128) ? (w & 1) * 64 : 0;

  // T1: bijective XCD-aware remap (valid since nwg % 8 == 0 for our launches)
  int nwg = gridDim.x * gridDim.y;
  int lin = blockIdx.y * gridDim.x + blockIdx.x;
  if ((nwg & 7) == 0) {
    int cpx = nwg >> 3;
    lin = (lin & 7) * cpx + (lin >> 3);
  }
  int bx = lin % gridDim.x, by = lin / gridDim.x;
  int bM = by * 128, bN = bx * BN;

  int srow   = (w << 3) + (lane >> 3);
  int schunk = (lane & 7) ^ ((lane >> 3) & 7);
  const unsigned short* aP = A  + (size_t)(bM + srow) * K + schunk * 8;
  const unsigned short* bP = Wt + (size_t)(bN + srow) * K + schunk * 8;

  int pc0 = (quad ^ (r & 7)) * 8;

  f32x4 acc[MT][4];
#pragma unroll
  for (int i = 0; i < MT; i++)
#pragma unroll
    for (int j = 0; j < 4; j++) acc[i][j] = f32x4{0.f, 0.f, 0.f, 0.f};

  for (int k0 = 0; k0 < K; k0 += 64) {
    __syncthreads();
#pragma unroll
    for (int p = 0; p < 4; p++)
      gl2lds16(aP + (size_t)(p * 32) * K + k0, &As[p * 32 + (w << 3)][0]);
#pragma unroll
    for (int p = 0; p < BN / 32; p++)
      gl2lds16(bP + (size_t)(p * 32) * K + k0, &Bs[p * 32 + (w << 3)][0]);
    __syncthreads();
#pragma unroll
    for (int kh = 0; kh < 2; kh++) {
      int pc = pc0 ^ (kh * 32);
      bf16x8 af[MT], bfr[4];
#pragma unroll
      for (int mt = 0; mt < MT; mt++)
        af[mt] = *(const bf16x8*)&As[rowbase + mt * 16 + r][pc];
#pragma unroll
      for (int nt = 0; nt < 4; nt++)
        bfr[nt] = *(const bf16x8*)&Bs[colbase + nt * 16 + r][pc];
#pragma unroll
      for (int mt = 0; mt < MT; mt++)
#pragma unroll
        for (int nt = 0; nt < 4; nt++)
          acc[mt][nt] = __builtin_amdgcn_mfma_f32_16x16x32_bf16(af[mt], bfr[nt], acc[mt][nt], 0, 0, 0);
    }
  }

#pragma unroll
  for (int mt = 0; mt < MT; mt++) {
#pragma unroll
    for (int nt = 0; nt < 4; nt++) {
#pragma unroll
      for (int i = 0; i < 4; i++) {
        int gm = bM + rowbase + mt * 16 + quad * 4 + i;
        int gn = bN + colbase + nt * 16 + r;
        float val = acc[mt][nt][i];
        if (MODE == 1) {
          outf[(size_t)gm * N + gn] = val + bias[gn] + resid[(size_t)gm * N + gn];
        } else {
          float t = val + bias[gn];
          float gl = 0.5f * t * (1.0f + erff(t * 0.70710678118f));
          outb0[(size_t)gm * N + gn] = f2bf(gl);
        }
      }
    }
  }
}

// ---------------- 256x256 8-phase pipelined GEMM (T2+T3+T4+T5) ----------------------
// MODE 0: QKV epilogue: q (scaled by 0.125*log2e) / k scattered bf16 [B,H,N,D];
//         v written DIRECTLY TRANSPOSED [B,H,D,N] as packed 8B stores (vtrans fused).
// MODE 2: outb0 = bf16(gelu_exact(acc + bias))
template <int MODE>
__global__ __launch_bounds__(512, 2) void gemm256_kernel(
    const unsigned short* __restrict__ A,    // [M][K] bf16
    const unsigned short* __restrict__ Wt,   // [N][K] bf16
    const float* __restrict__ bias,
    unsigned short* __restrict__ outb0,
    unsigned short* __restrict__ outb1,
    unsigned short* __restrict__ outb2,
    int M, int N, int K) {
  __shared__ __align__(16) short As[2][256][64];   // 64 KiB
  __shared__ __align__(16) short Bs[2][256][64];   // 64 KiB
  const int tid = threadIdx.x;
  const int w = tid >> 6, lane = tid & 63, r = lane & 15, quad = lane >> 4;
  const int wr = w >> 2, wc = w & 3;               // wave grid 2 (M) x 4 (N)
  const int bN = blockIdx.x * 256, bM = blockIdx.y * 256;

  const int srow   = (w << 3) + (lane >> 3);
  const int schunk = (lane & 7) ^ ((lane >> 3) & 7);
  const unsigned short* aSrc = A  + (size_t)(bM + srow) * K + schunk * 8;
  const unsigned short* bSrc = Wt + (size_t)(bN + srow) * K + schunk * 8;
  const int wrow = w << 3;

  const int ntiles = K >> 6;
  const int tmask  = ntiles - 1;

#define STAGE_H(t, h)                                                            \
  do {                                                                           \
    int b_ = (t) & 1, tt_ = (t) & tmask;                                         \
    if ((h) < 2) {                                                               \
      const unsigned short* p_ = aSrc + (size_t)((h) * 128) * K + tt_ * 64;      \
      gl2lds16(p_, &As[b_][(h) * 128 + wrow][0]);                                \
      gl2lds16(p_ + (size_t)64 * K, &As[b_][(h) * 128 + 64 + wrow][0]);          \
    } else {                                                                     \
      const unsigned short* p_ = bSrc + (size_t)(((h) - 2) * 128) * K + tt_ * 64;\
      gl2lds16(p_, &Bs[b_][((h) - 2) * 128 + wrow][0]);                          \
      gl2lds16(p_ + (size_t)64 * K, &Bs[b_][((h) - 2) * 128 + 64 + wrow][0]);    \
    }                                                                            \
  } while (0)

  f32x4 acc[8][4];
#pragma unroll
  for (int i = 0; i < 8; i++)
#pragma unroll
    for (int j = 0; j < 4; j++) acc[i][j] = f32x4{0.f, 0.f, 0.f, 0.f};

  bf16x8 af[4][2];
  bf16x8 bfr[4][2];

#define RD_A(b, msub)                                                            \
  {                                                                              \
    _Pragma("unroll") for (int mt_ = 0; mt_ < 4; mt_++)                          \
      _Pragma("unroll") for (int ks_ = 0; ks_ < 2; ks_++)                        \
        af[mt_][ks_] = *(const bf16x8*)&As[b][wr * 128 + (msub) * 64 + mt_ * 16 + r] \
                                          [((ks_ * 4 + quad) ^ (r & 7)) * 8];    \
  }
#define RD_B(b, nh)                                                              \
  {                                                                              \
    _Pragma("unroll") for (int nt_ = 0; nt_ < 2; nt_++)                          \
      _Pragma("unroll") for (int ks_ = 0; ks_ < 2; ks_++)                        \
        bfr[(nh) * 2 + nt_][ks_] =                                               \
            *(const bf16x8*)&Bs[b][wc * 64 + (nh) * 32 + nt_ * 16 + r]           \
                               [((ks_ * 4 + quad) ^ (r & 7)) * 8];               \
  }
#define MM_Q(msub, nh)                                                           \
  {                                                                              \
    _Pragma("unroll") for (int mt_ = 0; mt_ < 4; mt_++)                          \
      _Pragma("unroll") for (int nt_ = 0; nt_ < 2; nt_++)                        \
        _Pragma("unroll") for (int ks_ = 0; ks_ < 2; ks_++)                      \
          acc[(msub) * 4 + mt_][(nh) * 2 + nt_] =                                \
              __builtin_amdgcn_mfma_f32_16x16x32_bf16(                           \
                  af[mt_][ks_], bfr[(nh) * 2 + nt_][ks_],                        \
                  acc[(msub) * 4 + mt_][(nh) * 2 + nt_], 0, 0, 0);               \
  }

#define BARRIER() asm volatile("s_barrier" ::: "memory")
#define WAITL()   asm volatile("s_waitcnt lgkmcnt(0)" ::: "memory")
#define WAITV2()  asm volatile("s_waitcnt vmcnt(2)" ::: "memory")
#define PRIO1()   __builtin_amdgcn_s_setprio(1)
#define PRIO0()   __builtin_amdgcn_s_setprio(0)

  STAGE_H(0, 0); STAGE_H(0, 1); STAGE_H(0, 2); STAGE_H(0, 3);
  STAGE_H(1, 0);
  WAITV2();
  BARRIER();

  const int niter = ntiles >> 1;
  for (int i = 0; i < niter; i++) {
    const int tc = 2 * i;
    RD_A(0, 0); RD_B(0, 0);
    STAGE_H(tc + 1, 1);
    BARRIER(); WAITL();
    PRIO1(); MM_Q(0, 0); PRIO0();
    BARRIER();
    RD_B(0, 1);
    STAGE_H(tc + 1, 2);
    BARRIER(); WAITL();
    PRIO1(); MM_Q(0, 1); PRIO0();
    BARRIER();
    RD_A(0, 1);
    STAGE_H(tc + 1, 3);
    BARRIER(); WAITL();
    PRIO1(); MM_Q(1, 1); PRIO0();
    BARRIER();
    STAGE_H(tc + 2, 0);
    BARRIER(); WAITL();
    PRIO1(); MM_Q(1, 0); PRIO0();
    WAITV2();
    BARRIER();
    RD_A(1, 0); RD_B(1, 0);
    STAGE_H(tc + 2, 1);
    BARRIER(); WAITL();
    PRIO1(); MM_Q(0, 0); PRIO0();
    BARRIER();
    RD_B(1, 1);
    STAGE_H(tc + 2, 2);
    BARRIER(); WAITL();
    PRIO1(); MM_Q(0, 1); PRIO0();
    BARRIER();
    RD_A(1, 1);
    STAGE_H(tc + 2, 3);
    BARRIER(); WAITL();
    PRIO1(); MM_Q(1, 1); PRIO0();
    BARRIER();
    STAGE_H(tc + 3, 0);
    BARRIER(); WAITL();
    PRIO1(); MM_Q(1, 0); PRIO0();
    WAITV2();
    BARRIER();
  }

  // epilogue: D layout per 16x16 tile: row = quad*4+i, col = r
#pragma unroll
  for (int m = 0; m < 8; m++) {
#pragma unroll
    for (int n = 0; n < 4; n++) {
      int gm0 = bM + wr * 128 + m * 16 + quad * 4;
      int gn  = bN + wc * 64 + n * 16 + r;
      if (MODE == 0) {
        int s = gn >> 10, c = gn & 1023;
        int hh = c >> 6, d = c & 63;
        int b = gm0 >> 11, n0 = gm0 & 2047;
        if (s == 2) {
          // v: write transposed [B,H,D,N], 4 consecutive n packed into 8B
          unsigned int p0 = cvtpk(acc[m][n][0], acc[m][n][1]);
          unsigned int p1 = cvtpk(acc[m][n][2], acc[m][n][3]);
          *(uint2*)(outb2 + ((size_t)(b * H_ + hh) * D_ + d) * N_ + n0) = uint2{p0, p1};
        } else {
          unsigned short* dst = (s == 0) ? outb0 : outb1;
          float sc = (s == 0) ? 0.125f * LOG2E : 1.0f;
#pragma unroll
          for (int i2 = 0; i2 < 4; i2++) {
            size_t di = ((size_t)(b * H_ + hh) * N_ + n0 + i2) * D_ + d;
            dst[di] = f2bf(acc[m][n][i2] * sc);
          }
        }
      } else {
#pragma unroll
        for (int i2 = 0; i2 < 4; i2++) {
          float t = acc[m][n][i2] + bias[gn];
          float gl = 0.5f * t * (1.0f + erff(t * 0.70710678118f));
          outb0[(size_t)(gm0 + i2) * N + gn] = f2bf(gl);
        }
      }
    }
  }
#undef STAGE_H
#undef RD_A
#undef RD_B
#undef MM_Q
#undef BARRIER
#undef WAITL
#undef WAITV2
#undef PRIO1
#undef PRIO0
}

// ---------------- Flash attention, 8 waves / 256 q-rows per block -------------------
// q pre-scaled by 0.125*log2e -> softmax in exp2 domain. S^T formulation (mfma(K,Q)).
// LDS: double-buffered K and V^T tiles + private P buffer (96 KiB, 1 block/CU).
// Per KV-tile: {issue stage(t+1) | QK^T | online softmax (defer-max) | PV | syncthreads}
// -> single barrier per iter, HBM latency hidden under compute (T14).
__global__ __launch_bounds__(512, 2) void attn_kernel(const unsigned short* __restrict__ qb,
                                                      const unsigned short* __restrict__ kb,
                                                      const unsigned short* __restrict__ vtb,
                                                      unsigned short* __restrict__ ob) {
  __shared__ __align__(16) short Ks[2][128][64];   // 32 KB
  __shared__ __align__(16) short Vts[2][64][128];  // 32 KB (V^T: [d][key])
  __shared__ __align__(16) short Pl[8 * 16 * 128]; // 32 KB (wave-private 16x128 tiles)
  int tid = threadIdx.x;
  int w = tid >> 6, lane = tid & 63, r = lane & 15, quad = lane >> 4;
  int bh = blockIdx.x & 31, qt = blockIdx.x >> 5;  // XCD-local K/V reuse
  const unsigned short* qh  = qb  + (size_t)bh * N_ * D_;
  const unsigned short* kh  = kb  + (size_t)bh * N_ * D_;
  const unsigned short* vth = vtb + (size_t)bh * D_ * N_;
  int swz = r & 7;

  // Q fragments (B-operand): row = qt*256 + w*32 + mt*16 + r, k = ks*32 + quad*8 + j
  bf16x8 qf[2][2];
#pragma unroll
  for (int mt = 0; mt < 2; mt++)
#pragma unroll
    for (int ks = 0; ks < 2; ks++)
      qf[mt][ks] = *(const bf16x8*)(qh + (size_t)(qt * 256 + w * 32 + mt * 16 + r) * D_ + ks * 32 + quad * 8);

  float mst[2] = {-1e30f, -1e30f}, lst[2] = {0.f, 0.f};
  f32x4 oacc[2][4];
#pragma unroll
  for (int mt = 0; mt < 2; mt++)
#pragma unroll
    for (int nt = 0; nt < 4; nt++) oacc[mt][nt] = f32x4{0.f, 0.f, 0.f, 0.f};

  // staging bases (512 threads): K round = 64 rows x 64; V round = 32 rows x 128
  const unsigned short* kBase = kh + (size_t)(tid >> 3) * D_ + ((tid & 7) ^ ((tid >> 3) & 7)) * 8;
  const unsigned short* vBase = vth + (size_t)(tid >> 4) * N_ + ((tid & 15) ^ ((tid >> 4) & 7)) * 8;

  short* Plw = &Pl[0] + w * 2048;  // wave-private 16x128

  // prologue: stage tile 0 into buf 0
  gl2lds16(kBase,                        &Ks[0][(w << 3)][0]);
  gl2lds16(kBase + (size_t)64 * D_,      &Ks[0][64 + (w << 3)][0]);
  gl2lds16(vBase,                        &Vts[0][(w << 2)][0]);
  gl2lds16(vBase + (size_t)32 * N_,      &Vts[0][32 + (w << 2)][0]);
  __syncthreads();

  for (int t = 0; t < 16; t++) {
    const int cur = t & 1;
    // issue next tile's staging early (lands under this iter's compute)
    if (t < 15) {
      const int nb = cur ^ 1;
      gl2lds16(kBase + (size_t)(t + 1) * 128 * D_,                  &Ks[nb][(w << 3)][0]);
      gl2lds16(kBase + (size_t)((t + 1) * 128 + 64) * D_,           &Ks[nb][64 + (w << 3)][0]);
      gl2lds16(vBase + (size_t)(t + 1) * 128,                       &Vts[nb][(w << 2)][0]);
      gl2lds16(vBase + (size_t)(t + 1) * 128 + (size_t)32 * N_,     &Vts[nb][32 + (w << 2)][0]);
    }

    // S^T = K Q^T : D[key=quad*4+i][qrow=r]
    f32x4 sacc[2][8];
#pragma unroll
    for (int mt = 0; mt < 2; mt++)
#pragma unroll
      for (int nt = 0; nt < 8; nt++) sacc[mt][nt] = f32x4{0.f, 0.f, 0.f, 0.f};
#pragma unroll
    for (int ks = 0; ks < 2; ks++) {
#pragma unroll
      for (int nt = 0; nt < 8; nt++) {
        bf16x8 kfr = *(const bf16x8*)&Ks[cur][nt * 16 + r][((ks * 4 + quad) ^ swz) * 8];
#pragma unroll
        for (int mt = 0; mt < 2; mt++)
          sacc[mt][nt] = __builtin_amdgcn_mfma_f32_16x16x32_bf16(kfr, qf[mt][ks], sacc[mt][nt], 0, 0, 0);
      }
    }

    // V fragments for PV (hoisted; reused by both mt)
    bf16x8 vfr[4][4];
#pragma unroll
    for (int ks = 0; ks < 4; ks++)
#pragma unroll
      for (int nt2 = 0; nt2 < 4; nt2++)
        vfr[ks][nt2] = *(const bf16x8*)&Vts[cur][nt2 * 16 + r][((ks * 4 + quad) ^ swz) * 8];

    // online softmax (exp2 domain, defer-max: skip rescale if max grew < 8)
#pragma unroll
    for (int mt = 0; mt < 2; mt++) {
      float tm = -1e30f;
#pragma unroll
      for (int nt = 0; nt < 8; nt++)
#pragma unroll
        for (int i = 0; i < 4; i++) tm = fmaxf(tm, sacc[mt][nt][i]);
      tm = fmaxf(tm, __shfl_xor(tm, 16));
      tm = fmaxf(tm, __shfl_xor(tm, 32));
      if (__ballot(tm > mst[mt] + 8.0f)) {
        float mnew = fmaxf(mst[mt], tm);
        float alpha = exp2a(mst[mt] - mnew);
        mst[mt] = mnew;
        lst[mt] *= alpha;
#pragma unroll
        for (int i = 0; i < 4; i++) {
          float av = __shfl(alpha, (lane & 48) | (quad * 4 + i));
#pragma unroll
          for (int nt2 = 0; nt2 < 4; nt2++) oacc[mt][nt2][i] *= av;
        }
      }
      float m = mst[mt];
      float rs = 0.f;
#pragma unroll
      for (int nt = 0; nt < 8; nt++)
#pragma unroll
        for (int i = 0; i < 4; i++) {
          float p = exp2a(sacc[mt][nt][i] - m);
          sacc[mt][nt][i] = p;
          rs += p;
        }
      rs += __shfl_xor(rs, 16);
      rs += __shfl_xor(rs, 32);
      lst[mt] += rs;
    }

    // P -> LDS (wave-private) -> PV
#pragma unroll
    for (int mt = 0; mt < 2; mt++) {
#pragma unroll
      for (int nt = 0; nt < 8; nt++) {
        uint2 pw;
        pw.x = cvtpk(sacc[mt][nt][0], sacc[mt][nt][1]);
        pw.y = cvtpk(sacc[mt][nt][2], sacc[mt][nt][3]);
        *(uint2*)&Plw[r * 128 + (((nt * 2 + (quad >> 1)) ^ swz) * 8) + (quad & 1) * 4] = pw;
      }
      asm volatile("" ::: "memory");  // keep reads after writes (wave-private region)
#pragma unroll
      for (int ks = 0; ks < 4; ks++) {
        bf16x8 pfr = *(const bf16x8*)&Plw[r * 128 + ((ks * 4 + quad) ^ swz) * 8];
#pragma unroll
        for (int nt2 = 0; nt2 < 4; nt2++)
          oacc[mt][nt2] = __builtin_amdgcn_mfma_f32_16x16x32_bf16(pfr, vfr[ks][nt2], oacc[mt][nt2], 0, 0, 0);
      }
      asm volatile("" ::: "memory");  // keep mt=1 writes after mt=0 reads
    }

    // staged t+1 landed (issued ~2000 cy ago); all waves done reading buf cur
    __syncthreads();
  }

  // epilogue: o[b][n][h*64+d] bf16;  O C-layout row=quad*4+i, col=r
  int bb = bh >> 4, hh = bh & 15;
#pragma unroll
  for (int mt = 0; mt < 2; mt++) {
#pragma unroll
    for (int i = 0; i < 4; i++) {
      float li = __shfl(lst[mt], (lane & 48) | (quad * 4 + i));
      float inv = 1.0f / li;
      int row = qt * 256 + w * 32 + mt * 16 + quad * 4 + i;
#pragma unroll
      for (int nt2 = 0; nt2 < 4; nt2++) {
        int d = nt2 * 16 + r;
        ob[((size_t)bb * N_ + row) * C_ + hh * D_ + d] = f2bf(oacc[mt][nt2][i] * inv);
      }
    }
  }
}

// ------------------------------------ launch ---------------------------------------
extern "C" void kernel_launch(void* const* d_in, const int* in_sizes, int n_in,
                              void* d_out, int out_size, void* d_ws, size_t ws_size,
                              hipStream_t stream) {
  const float* x     = (const float*)d_in[0];
  const float* ln1g  = (const float*)d_in[1];
  const float* ln1b  = (const float*)d_in[2];
  const float* wqkv  = (const float*)d_in[3];   // [1024][3072]
  const float* wproj = (const float*)d_in[4];   // [1024][1024]
  const float* bproj = (const float*)d_in[5];
  const float* ln2g  = (const float*)d_in[6];
  const float* ln2b  = (const float*)d_in[7];
  const float* wfc1  = (const float*)d_in[8];   // [1024][4096]
  const float* bfc1  = (const float*)d_in[9];
  const float* wfc2  = (const float*)d_in[10];  // [4096][1024]
  const float* bfc2  = (const float*)d_in[11];
  float* out = (float*)d_out;

  const size_t MB = 1u << 20;
  if (ws_size < 88 * MB) return;  // layout below needs 88 MB
  char* w = (char*)d_ws;
  unsigned short* xn    = (unsigned short*)(w + 0 * MB);   // 8 MB
  unsigned short* qbuf  = (unsigned short*)(w + 8 * MB);   // 8 MB
  unsigned short* kbuf  = (unsigned short*)(w + 16 * MB);  // 8 MB
  unsigned short* hbuf  = (unsigned short*)(w + 0 * MB);   // 32 MB, aliases xn/q/k (dead by fc1)
  unsigned short* obuf  = (unsigned short*)(w + 32 * MB);  // 8 MB
  float*          x2    = (float*)         (w + 40 * MB);  // 16 MB
  unsigned short* xn2   = (unsigned short*)(w + 56 * MB);  // 8 MB
  unsigned short* vtb   = (unsigned short*)(w + 56 * MB);  // 8 MB, dead before xn2 is written
  unsigned short* wqkvt = (unsigned short*)(w + 64 * MB);  // 6 MB
  unsigned short* wprjt = (unsigned short*)(w + 70 * MB);  // 2 MB
  unsigned short* wfc1t = (unsigned short*)(w + 72 * MB);  // 8 MB
  unsigned short* wfc2t = (unsigned short*)(w + 80 * MB);  // 8 MB

  ln_kernel<<<M_ / 4, 256, 0, stream>>>(x, ln1g, ln1b, xn);
  wtrans_all<<<12288, dim3(32, 8), 0, stream>>>(wqkv, wproj, wfc1, wfc2,
                                                wqkvt, wprjt, wfc1t, wfc2t);

  // QKV (v written directly transposed into vtb; q pre-scaled by 0.125*log2e)
  gemm256_kernel<0><<<dim3(3 * C_ / 256, M_ / 256), 512, 0, stream>>>(
      xn, wqkvt, nullptr, qbuf, kbuf, vtb, M_, 3 * C_, C_);
  attn_kernel<<<B_ * H_ * (N_ / 256), 512, 0, stream>>>(qbuf, kbuf, vtb, obuf);
  // proj: m97 128x128 structure, 256 blocks (1/CU), XCD-swizzled
  gemm_kernel<1, 128><<<dim3(C_ / 128, M_ / 128), 256, 0, stream>>>(
      obuf, wprjt, bproj, x, x2, nullptr, M_, C_, C_);
  ln_kernel<<<M_ / 4, 256, 0, stream>>>(x2, ln2g, ln2b, xn2);
  gemm256_kernel<2><<<dim3(HID_ / 256, M_ / 256), 512, 0, stream>>>(
      xn2, wfc1t, bfc1, hbuf, nullptr, nullptr, M_, HID_, C_);
  // fc2: m97 128x128 structure, 256 blocks (1/CU), XCD-swizzled
  gemm_kernel<1, 128><<<dim3(C_ / 128, M_ / 128), 256, 0, stream>>>(
      hbuf, wfc2t, bfc2, x2, out, nullptr, M_, C_, HID_);
}

// Round 4
// 342.495 us; speedup vs baseline: 1.0869x; 1.0869x over previous
//
#include <hip/hip_runtime.h>

#define B_   2
#define N_   2048
#define C_   1024
#define H_   16
#define D_   64
#define HID_ 4096
#define M_   (B_ * N_)   // 4096 rows

typedef __attribute__((ext_vector_type(8))) short bf16x8;  // 8 bf16 = 4 VGPRs
typedef __attribute__((ext_vector_type(4))) float f32x4;

__device__ __forceinline__ unsigned short f2bf(float f) {
  unsigned int u = __builtin_bit_cast(unsigned int, f);
  u += 0x7fffu + ((u >> 16) & 1u);   // RNE
  return (unsigned short)(u >> 16);
}

// pack 2 fp32 -> 2 bf16 (RNE), single instruction
__device__ __forceinline__ unsigned int cvtpk(float a, float b) {
  unsigned int r;
  asm("v_cvt_pk_bf16_f32 %0, %1, %2" : "=v"(r) : "v"(a), "v"(b));
  return r;
}

__device__ __forceinline__ float exp2a(float x) {
  float r;
  asm("v_exp_f32 %0, %1" : "=v"(r) : "v"(x));
  return r;
}

// async global->LDS, 16B per lane; LDS dest = wave-uniform base + lane*16
__device__ __forceinline__ void gl2lds16(const void* g, void* l) {
  __builtin_amdgcn_global_load_lds(
      (const __attribute__((address_space(1))) unsigned int*)g,
      (__attribute__((address_space(3))) unsigned int*)l, 16, 0, 0);
}

#define LOG2E 1.44269504088896f

// ---------------- LayerNorm (fp32 in -> bf16 out), one WAVE per row ----------------
__global__ __launch_bounds__(256) void ln_kernel(const float* __restrict__ x,
                                                 const float* __restrict__ g,
                                                 const float* __restrict__ bta,
                                                 unsigned short* __restrict__ out) {
  int row  = blockIdx.x * 4 + (threadIdx.x >> 6);
  int lane = threadIdx.x & 63;
  const float* xr = x + (size_t)row * C_;
  float4 v[4];
  float s1 = 0.f, s2 = 0.f;
#pragma unroll
  for (int j = 0; j < 4; j++) {
    v[j] = *(const float4*)(xr + j * 256 + lane * 4);
    s1 += v[j].x + v[j].y + v[j].z + v[j].w;
    s2 += v[j].x * v[j].x + v[j].y * v[j].y + v[j].z * v[j].z + v[j].w * v[j].w;
  }
#pragma unroll
  for (int m = 1; m < 64; m <<= 1) { s1 += __shfl_xor(s1, m); s2 += __shfl_xor(s2, m); }
  float mu  = s1 * (1.0f / C_);
  float var = s2 * (1.0f / C_) - mu * mu;
  float rs  = rsqrtf(var + 1e-5f);
#pragma unroll
  for (int j = 0; j < 4; j++) {
    const float4 gv = *(const float4*)(g + j * 256 + lane * 4);
    const float4 bv = *(const float4*)(bta + j * 256 + lane * 4);
    ushort4 o;
    o.x = f2bf((v[j].x - mu) * rs * gv.x + bv.x);
    o.y = f2bf((v[j].y - mu) * rs * gv.y + bv.y);
    o.z = f2bf((v[j].z - mu) * rs * gv.z + bv.z);
    o.w = f2bf((v[j].w - mu) * rs * gv.w + bv.w);
    *(ushort4*)(out + (size_t)row * C_ + j * 256 + lane * 4) = o;
  }
}

// ------------- All 4 weight transposes (fp32->bf16, W[K][N]->Wt[N][K]) in ONE dispatch
__global__ __launch_bounds__(256) void wtrans_all(
    const float* __restrict__ w0, const float* __restrict__ w1,
    const float* __restrict__ w2, const float* __restrict__ w3,
    unsigned short* __restrict__ o0, unsigned short* __restrict__ o1,
    unsigned short* __restrict__ o2, unsigned short* __restrict__ o3) {
  int id = blockIdx.x;
  const float* W; unsigned short* Wt; int K, N, rel;
  if (id < 3072)      { W = w0; Wt = o0; K = 1024; N = 3072; rel = id; }
  else if (id < 4096) { W = w1; Wt = o1; K = 1024; N = 1024; rel = id - 3072; }
  else if (id < 8192) { W = w2; Wt = o2; K = 1024; N = 4096; rel = id - 4096; }
  else                { W = w3; Wt = o3; K = 4096; N = 1024; rel = id - 8192; }
  int nx = N >> 5;
  int n0 = (rel % nx) * 32, k0 = (rel / nx) * 32;
  __shared__ float t[32][33];
  int tx = threadIdx.x, ty = threadIdx.y;  // 32 x 8
#pragma unroll
  for (int j = 0; j < 4; j++)
    t[ty + j * 8][tx] = W[(size_t)(k0 + ty + j * 8) * N + n0 + tx];
  __syncthreads();
#pragma unroll
  for (int j = 0; j < 4; j++)
    Wt[(size_t)(n0 + ty + j * 8) * K + k0 + tx] = f2bf(t[tx][ty + j * 8]);
}

// ------- Double-buffered BN=64 GEMM (proj / fc2): outf = acc + bias + resid --------
// 4 waves, wave = 32x64 output. LDS dbuf (48 KiB -> still 2 blocks/CU w/ grid 512).
// Per K-step: {issue stage(k+1) -> buf^1 | ds_read + 16 MFMA on buf | syncthreads}.
// The k+1 loads are in flight during k's compute, so the barrier drain is cheap (T14).
// T1 XCD swizzle: contiguous M-chunk per XCD -> A slice L2-resident (FETCH 143->~60MB).
__global__ __launch_bounds__(256) void gemm_db_kernel(
    const unsigned short* __restrict__ A,    // [M][K] bf16
    const unsigned short* __restrict__ Wt,   // [N][K] bf16
    const float* __restrict__ bias,
    const float* __restrict__ resid,
    float* __restrict__ outf,
    int M, int N, int K) {
  __shared__ __align__(16) short As[2][128][64];   // 32 KiB
  __shared__ __align__(16) short Bs[2][64][64];    // 16 KiB
  int tid = threadIdx.x;
  int w = tid >> 6, lane = tid & 63, r = lane & 15, quad = lane >> 4;
  int rowbase = w * 32;

  // T1: bijective XCD-aware remap (nwg % 8 == 0 for our launches: 512)
  int nwg = gridDim.x * gridDim.y;
  int lin = blockIdx.y * gridDim.x + blockIdx.x;
  int cpx = nwg >> 3;
  lin = (lin & 7) * cpx + (lin >> 3);
  int bx = lin % gridDim.x, by = lin / gridDim.x;
  int bM = by * 128, bN = bx * 64;

  int srow   = (w << 3) + (lane >> 3);
  int schunk = (lane & 7) ^ ((lane >> 3) & 7);
  const unsigned short* aP = A  + (size_t)(bM + srow) * K + schunk * 8;
  const unsigned short* bP = Wt + (size_t)(bN + srow) * K + schunk * 8;

  int pc0 = (quad ^ (r & 7)) * 8;

  f32x4 acc[2][4];
#pragma unroll
  for (int i = 0; i < 2; i++)
#pragma unroll
    for (int j = 0; j < 4; j++) acc[i][j] = f32x4{0.f, 0.f, 0.f, 0.f};

#define STAGE_DB(kt, b)                                                       \
  do {                                                                        \
    int k0_ = (kt) * 64;                                                      \
    _Pragma("unroll") for (int p = 0; p < 4; p++)                             \
      gl2lds16(aP + (size_t)(p * 32) * K + k0_, &As[b][p * 32 + (w << 3)][0]);\
    _Pragma("unroll") for (int p = 0; p < 2; p++)                             \
      gl2lds16(bP + (size_t)(p * 32) * K + k0_, &Bs[b][p * 32 + (w << 3)][0]);\
  } while (0)

  const int nk = K >> 6;
  STAGE_DB(0, 0);
  __syncthreads();

  for (int kt = 0; kt < nk; kt++) {
    const int cb = kt & 1;
    if (kt + 1 < nk) STAGE_DB(kt + 1, cb ^ 1);
#pragma unroll
    for (int kh = 0; kh < 2; kh++) {
      int pc = pc0 ^ (kh * 32);
      bf16x8 af[2], bfr[4];
#pragma unroll
      for (int mt = 0; mt < 2; mt++)
        af[mt] = *(const bf16x8*)&As[cb][rowbase + mt * 16 + r][pc];
#pragma unroll
      for (int nt = 0; nt < 4; nt++)
        bfr[nt] = *(const bf16x8*)&Bs[cb][nt * 16 + r][pc];
#pragma unroll
      for (int mt = 0; mt < 2; mt++)
#pragma unroll
        for (int nt = 0; nt < 4; nt++)
          acc[mt][nt] = __builtin_amdgcn_mfma_f32_16x16x32_bf16(af[mt], bfr[nt], acc[mt][nt], 0, 0, 0);
    }
    __syncthreads();   // drains vmcnt: stage(k+1) landed; all reads of buf cb done
  }

#pragma unroll
  for (int mt = 0; mt < 2; mt++) {
#pragma unroll
    for (int nt = 0; nt < 4; nt++) {
#pragma unroll
      for (int i = 0; i < 4; i++) {
        int gm = bM + rowbase + mt * 16 + quad * 4 + i;
        int gn = bN + nt * 16 + r;
        outf[(size_t)gm * N + gn] = acc[mt][nt][i] + bias[gn] + resid[(size_t)gm * N + gn];
      }
    }
  }
#undef STAGE_DB
}

// ---------------- 256x256 8-phase pipelined GEMM (T1+T2+T3+T4+T5) -------------------
// MODE 0: QKV epilogue: q (scaled by 0.125*log2e) / k scattered bf16 [B,H,N,D];
//         v written DIRECTLY TRANSPOSED [B,H,D,N] as packed 8B stores (vtrans fused).
// MODE 2: outb0 = bf16(gelu_exact(acc + bias))
template <int MODE>
__global__ __launch_bounds__(512, 2) void gemm256_kernel(
    const unsigned short* __restrict__ A,    // [M][K] bf16
    const unsigned short* __restrict__ Wt,   // [N][K] bf16
    const float* __restrict__ bias,
    unsigned short* __restrict__ outb0,
    unsigned short* __restrict__ outb1,
    unsigned short* __restrict__ outb2,
    int M, int N, int K) {
  __shared__ __align__(16) short As[2][256][64];   // 64 KiB
  __shared__ __align__(16) short Bs[2][256][64];   // 64 KiB
  const int tid = threadIdx.x;
  const int w = tid >> 6, lane = tid & 63, r = lane & 15, quad = lane >> 4;
  const int wr = w >> 2, wc = w & 3;               // wave grid 2 (M) x 4 (N)

  // T1: bijective XCD-aware remap (nwg = 192 or 256, both % 8 == 0)
  int nwg = gridDim.x * gridDim.y;
  int lin = blockIdx.y * gridDim.x + blockIdx.x;
  int cpx = nwg >> 3;
  lin = (lin & 7) * cpx + (lin >> 3);
  const int bN = (lin % gridDim.x) * 256, bM = (lin / gridDim.x) * 256;

  const int srow   = (w << 3) + (lane >> 3);
  const int schunk = (lane & 7) ^ ((lane >> 3) & 7);
  const unsigned short* aSrc = A  + (size_t)(bM + srow) * K + schunk * 8;
  const unsigned short* bSrc = Wt + (size_t)(bN + srow) * K + schunk * 8;
  const int wrow = w << 3;

  const int ntiles = K >> 6;
  const int tmask  = ntiles - 1;

#define STAGE_H(t, h)                                                            \
  do {                                                                           \
    int b_ = (t) & 1, tt_ = (t) & tmask;                                         \
    if ((h) < 2) {                                                               \
      const unsigned short* p_ = aSrc + (size_t)((h) * 128) * K + tt_ * 64;      \
      gl2lds16(p_, &As[b_][(h) * 128 + wrow][0]);                                \
      gl2lds16(p_ + (size_t)64 * K, &As[b_][(h) * 128 + 64 + wrow][0]);          \
    } else {                                                                     \
      const unsigned short* p_ = bSrc + (size_t)(((h) - 2) * 128) * K + tt_ * 64;\
      gl2lds16(p_, &Bs[b_][((h) - 2) * 128 + wrow][0]);                          \
      gl2lds16(p_ + (size_t)64 * K, &Bs[b_][((h) - 2) * 128 + 64 + wrow][0]);    \
    }                                                                            \
  } while (0)

  f32x4 acc[8][4];
#pragma unroll
  for (int i = 0; i < 8; i++)
#pragma unroll
    for (int j = 0; j < 4; j++) acc[i][j] = f32x4{0.f, 0.f, 0.f, 0.f};

  bf16x8 af[4][2];
  bf16x8 bfr[4][2];

#define RD_A(b, msub)                                                            \
  {                                                                              \
    _Pragma("unroll") for (int mt_ = 0; mt_ < 4; mt_++)                          \
      _Pragma("unroll") for (int ks_ = 0; ks_ < 2; ks_++)                        \
        af[mt_][ks_] = *(const bf16x8*)&As[b][wr * 128 + (msub) * 64 + mt_ * 16 + r] \
                                          [((ks_ * 4 + quad) ^ (r & 7)) * 8];    \
  }
#define RD_B(b, nh)                                                              \
  {                                                                              \
    _Pragma("unroll") for (int nt_ = 0; nt_ < 2; nt_++)                          \
      _Pragma("unroll") for (int ks_ = 0; ks_ < 2; ks_++)                        \
        bfr[(nh) * 2 + nt_][ks_] =                                               \
            *(const bf16x8*)&Bs[b][wc * 64 + (nh) * 32 + nt_ * 16 + r]           \
                               [((ks_ * 4 + quad) ^ (r & 7)) * 8];               \
  }
#define MM_Q(msub, nh)                                                           \
  {                                                                              \
    _Pragma("unroll") for (int mt_ = 0; mt_ < 4; mt_++)                          \
      _Pragma("unroll") for (int nt_ = 0; nt_ < 2; nt_++)                        \
        _Pragma("unroll") for (int ks_ = 0; ks_ < 2; ks_++)                      \
          acc[(msub) * 4 + mt_][(nh) * 2 + nt_] =                                \
              __builtin_amdgcn_mfma_f32_16x16x32_bf16(                           \
                  af[mt_][ks_], bfr[(nh) * 2 + nt_][ks_],                        \
                  acc[(msub) * 4 + mt_][(nh) * 2 + nt_], 0, 0, 0);               \
  }

#define BARRIER() asm volatile("s_barrier" ::: "memory")
#define WAITL()   asm volatile("s_waitcnt lgkmcnt(0)" ::: "memory")
#define WAITV2()  asm volatile("s_waitcnt vmcnt(2)" ::: "memory")
#define PRIO1()   __builtin_amdgcn_s_setprio(1)
#define PRIO0()   __builtin_amdgcn_s_setprio(0)

  STAGE_H(0, 0); STAGE_H(0, 1); STAGE_H(0, 2); STAGE_H(0, 3);
  STAGE_H(1, 0);
  WAITV2();
  BARRIER();

  const int niter = ntiles >> 1;
  for (int i = 0; i < niter; i++) {
    const int tc = 2 * i;
    RD_A(0, 0); RD_B(0, 0);
    STAGE_H(tc + 1, 1);
    BARRIER(); WAITL();
    PRIO1(); MM_Q(0, 0); PRIO0();
    BARRIER();
    RD_B(0, 1);
    STAGE_H(tc + 1, 2);
    BARRIER(); WAITL();
    PRIO1(); MM_Q(0, 1); PRIO0();
    BARRIER();
    RD_A(0, 1);
    STAGE_H(tc + 1, 3);
    BARRIER(); WAITL();
    PRIO1(); MM_Q(1, 1); PRIO0();
    BARRIER();
    STAGE_H(tc + 2, 0);
    BARRIER(); WAITL();
    PRIO1(); MM_Q(1, 0); PRIO0();
    WAITV2();
    BARRIER();
    RD_A(1, 0); RD_B(1, 0);
    STAGE_H(tc + 2, 1);
    BARRIER(); WAITL();
    PRIO1(); MM_Q(0, 0); PRIO0();
    BARRIER();
    RD_B(1, 1);
    STAGE_H(tc + 2, 2);
    BARRIER(); WAITL();
    PRIO1(); MM_Q(0, 1); PRIO0();
    BARRIER();
    RD_A(1, 1);
    STAGE_H(tc + 2, 3);
    BARRIER(); WAITL();
    PRIO1(); MM_Q(1, 1); PRIO0();
    BARRIER();
    STAGE_H(tc + 3, 0);
    BARRIER(); WAITL();
    PRIO1(); MM_Q(1, 0); PRIO0();
    WAITV2();
    BARRIER();
  }

  // epilogue: D layout per 16x16 tile: row = quad*4+i, col = r
#pragma unroll
  for (int m = 0; m < 8; m++) {
#pragma unroll
    for (int n = 0; n < 4; n++) {
      int gm0 = bM + wr * 128 + m * 16 + quad * 4;
      int gn  = bN + wc * 64 + n * 16 + r;
      if (MODE == 0) {
        int s = gn >> 10, c = gn & 1023;
        int hh = c >> 6, d = c & 63;
        int b = gm0 >> 11, n0 = gm0 & 2047;
        if (s == 2) {
          // v: write transposed [B,H,D,N], 4 consecutive n packed into 8B
          unsigned int p0 = cvtpk(acc[m][n][0], acc[m][n][1]);
          unsigned int p1 = cvtpk(acc[m][n][2], acc[m][n][3]);
          *(uint2*)(outb2 + ((size_t)(b * H_ + hh) * D_ + d) * N_ + n0) = uint2{p0, p1};
        } else {
          unsigned short* dst = (s == 0) ? outb0 : outb1;
          float sc = (s == 0) ? 0.125f * LOG2E : 1.0f;
#pragma unroll
          for (int i2 = 0; i2 < 4; i2++) {
            size_t di = ((size_t)(b * H_ + hh) * N_ + n0 + i2) * D_ + d;
            dst[di] = f2bf(acc[m][n][i2] * sc);
          }
        }
      } else {
#pragma unroll
        for (int i2 = 0; i2 < 4; i2++) {
          float t = acc[m][n][i2] + bias[gn];
          float gl = 0.5f * t * (1.0f + erff(t * 0.70710678118f));
          outb0[(size_t)(gm0 + i2) * N + gn] = f2bf(gl);
        }
      }
    }
  }
#undef STAGE_H
#undef RD_A
#undef RD_B
#undef MM_Q
#undef BARRIER
#undef WAITL
#undef WAITV2
#undef PRIO1
#undef PRIO0
}

// ---------------- Flash attention, 8 waves / 256 q-rows per block -------------------
// q pre-scaled by 0.125*log2e -> softmax in exp2 domain. S^T formulation (mfma(K,Q)).
// LDS: double-buffered K and V^T tiles + private P buffer (96 KiB, 1 block/CU).
// Per KV-tile: {issue stage(t+1) | QK^T | online softmax (defer-max) | PV | syncthreads}
// -> single barrier per iter, HBM latency hidden under compute (T14).
__global__ __launch_bounds__(512, 2) void attn_kernel(const unsigned short* __restrict__ qb,
                                                      const unsigned short* __restrict__ kb,
                                                      const unsigned short* __restrict__ vtb,
                                                      unsigned short* __restrict__ ob) {
  __shared__ __align__(16) short Ks[2][128][64];   // 32 KB
  __shared__ __align__(16) short Vts[2][64][128];  // 32 KB (V^T: [d][key])
  __shared__ __align__(16) short Pl[8 * 16 * 128]; // 32 KB (wave-private 16x128 tiles)
  int tid = threadIdx.x;
  int w = tid >> 6, lane = tid & 63, r = lane & 15, quad = lane >> 4;
  int bh = blockIdx.x & 31, qt = blockIdx.x >> 5;  // XCD-local K/V reuse
  const unsigned short* qh  = qb  + (size_t)bh * N_ * D_;
  const unsigned short* kh  = kb  + (size_t)bh * N_ * D_;
  const unsigned short* vth = vtb + (size_t)bh * D_ * N_;
  int swz = r & 7;

  // Q fragments (B-operand): row = qt*256 + w*32 + mt*16 + r, k = ks*32 + quad*8 + j
  bf16x8 qf[2][2];
#pragma unroll
  for (int mt = 0; mt < 2; mt++)
#pragma unroll
    for (int ks = 0; ks < 2; ks++)
      qf[mt][ks] = *(const bf16x8*)(qh + (size_t)(qt * 256 + w * 32 + mt * 16 + r) * D_ + ks * 32 + quad * 8);

  float mst[2] = {-1e30f, -1e30f}, lst[2] = {0.f, 0.f};
  f32x4 oacc[2][4];
#pragma unroll
  for (int mt = 0; mt < 2; mt++)
#pragma unroll
    for (int nt = 0; nt < 4; nt++) oacc[mt][nt] = f32x4{0.f, 0.f, 0.f, 0.f};

  // staging bases (512 threads): K round = 64 rows x 64; V round = 32 rows x 128
  const unsigned short* kBase = kh + (size_t)(tid >> 3) * D_ + ((tid & 7) ^ ((tid >> 3) & 7)) * 8;
  const unsigned short* vBase = vth + (size_t)(tid >> 4) * N_ + ((tid & 15) ^ ((tid >> 4) & 7)) * 8;

  short* Plw = &Pl[0] + w * 2048;  // wave-private 16x128

  // prologue: stage tile 0 into buf 0
  gl2lds16(kBase,                        &Ks[0][(w << 3)][0]);
  gl2lds16(kBase + (size_t)64 * D_,      &Ks[0][64 + (w << 3)][0]);
  gl2lds16(vBase,                        &Vts[0][(w << 2)][0]);
  gl2lds16(vBase + (size_t)32 * N_,      &Vts[0][32 + (w << 2)][0]);
  __syncthreads();

  for (int t = 0; t < 16; t++) {
    const int cur = t & 1;
    // issue next tile's staging early (lands under this iter's compute)
    if (t < 15) {
      const int nb = cur ^ 1;
      gl2lds16(kBase + (size_t)(t + 1) * 128 * D_,                  &Ks[nb][(w << 3)][0]);
      gl2lds16(kBase + (size_t)((t + 1) * 128 + 64) * D_,           &Ks[nb][64 + (w << 3)][0]);
      gl2lds16(vBase + (size_t)(t + 1) * 128,                       &Vts[nb][(w << 2)][0]);
      gl2lds16(vBase + (size_t)(t + 1) * 128 + (size_t)32 * N_,     &Vts[nb][32 + (w << 2)][0]);
    }

    // S^T = K Q^T : D[key=quad*4+i][qrow=r]
    f32x4 sacc[2][8];
#pragma unroll
    for (int mt = 0; mt < 2; mt++)
#pragma unroll
      for (int nt = 0; nt < 8; nt++) sacc[mt][nt] = f32x4{0.f, 0.f, 0.f, 0.f};
#pragma unroll
    for (int ks = 0; ks < 2; ks++) {
#pragma unroll
      for (int nt = 0; nt < 8; nt++) {
        bf16x8 kfr = *(const bf16x8*)&Ks[cur][nt * 16 + r][((ks * 4 + quad) ^ swz) * 8];
#pragma unroll
        for (int mt = 0; mt < 2; mt++)
          sacc[mt][nt] = __builtin_amdgcn_mfma_f32_16x16x32_bf16(kfr, qf[mt][ks], sacc[mt][nt], 0, 0, 0);
      }
    }

    // V fragments for PV (hoisted; reused by both mt)
    bf16x8 vfr[4][4];
#pragma unroll
    for (int ks = 0; ks < 4; ks++)
#pragma unroll
      for (int nt2 = 0; nt2 < 4; nt2++)
        vfr[ks][nt2] = *(const bf16x8*)&Vts[cur][nt2 * 16 + r][((ks * 4 + quad) ^ swz) * 8];

    // online softmax (exp2 domain, defer-max: skip rescale if max grew < 8)
#pragma unroll
    for (int mt = 0; mt < 2; mt++) {
      float tm = -1e30f;
#pragma unroll
      for (int nt = 0; nt < 8; nt++)
#pragma unroll
        for (int i = 0; i < 4; i++) tm = fmaxf(tm, sacc[mt][nt][i]);
      tm = fmaxf(tm, __shfl_xor(tm, 16));
      tm = fmaxf(tm, __shfl_xor(tm, 32));
      if (__ballot(tm > mst[mt] + 8.0f)) {
        float mnew = fmaxf(mst[mt], tm);
        float alpha = exp2a(mst[mt] - mnew);
        mst[mt] = mnew;
        lst[mt] *= alpha;
#pragma unroll
        for (int i = 0; i < 4; i++) {
          float av = __shfl(alpha, (lane & 48) | (quad * 4 + i));
#pragma unroll
          for (int nt2 = 0; nt2 < 4; nt2++) oacc[mt][nt2][i] *= av;
        }
      }
      float m = mst[mt];
      float rs = 0.f;
#pragma unroll
      for (int nt = 0; nt < 8; nt++)
#pragma unroll
        for (int i = 0; i < 4; i++) {
          float p = exp2a(sacc[mt][nt][i] - m);
          sacc[mt][nt][i] = p;
          rs += p;
        }
      rs += __shfl_xor(rs, 16);
      rs += __shfl_xor(rs, 32);
      lst[mt] += rs;
    }

    // P -> LDS (wave-private) -> PV
#pragma unroll
    for (int mt = 0; mt < 2; mt++) {
#pragma unroll
      for (int nt = 0; nt < 8; nt++) {
        uint2 pw;
        pw.x = cvtpk(sacc[mt][nt][0], sacc[mt][nt][1]);
        pw.y = cvtpk(sacc[mt][nt][2], sacc[mt][nt][3]);
        *(uint2*)&Plw[r * 128 + (((nt * 2 + (quad >> 1)) ^ swz) * 8) + (quad & 1) * 4] = pw;
      }
      asm volatile("" ::: "memory");  // keep reads after writes (wave-private region)
#pragma unroll
      for (int ks = 0; ks < 4; ks++) {
        bf16x8 pfr = *(const bf16x8*)&Plw[r * 128 + ((ks * 4 + quad) ^ swz) * 8];
#pragma unroll
        for (int nt2 = 0; nt2 < 4; nt2++)
          oacc[mt][nt2] = __builtin_amdgcn_mfma_f32_16x16x32_bf16(pfr, vfr[ks][nt2], oacc[mt][nt2], 0, 0, 0);
      }
      asm volatile("" ::: "memory");  // keep mt=1 writes after mt=0 reads
    }

    // staged t+1 landed (issued ~2000 cy ago); all waves done reading buf cur
    __syncthreads();
  }

  // epilogue: o[b][n][h*64+d] bf16;  O C-layout row=quad*4+i, col=r
  int bb = bh >> 4, hh = bh & 15;
#pragma unroll
  for (int mt = 0; mt < 2; mt++) {
#pragma unroll
    for (int i = 0; i < 4; i++) {
      float li = __shfl(lst[mt], (lane & 48) | (quad * 4 + i));
      float inv = 1.0f / li;
      int row = qt * 256 + w * 32 + mt * 16 + quad * 4 + i;
#pragma unroll
      for (int nt2 = 0; nt2 < 4; nt2++) {
        int d = nt2 * 16 + r;
        ob[((size_t)bb * N_ + row) * C_ + hh * D_ + d] = f2bf(oacc[mt][nt2][i] * inv);
      }
    }
  }
}

// ------------------------------------ launch ---------------------------------------
extern "C" void kernel_launch(void* const* d_in, const int* in_sizes, int n_in,
                              void* d_out, int out_size, void* d_ws, size_t ws_size,
                              hipStream_t stream) {
  const float* x     = (const float*)d_in[0];
  const float* ln1g  = (const float*)d_in[1];
  const float* ln1b  = (const float*)d_in[2];
  const float* wqkv  = (const float*)d_in[3];   // [1024][3072]
  const float* wproj = (const float*)d_in[4];   // [1024][1024]
  const float* bproj = (const float*)d_in[5];
  const float* ln2g  = (const float*)d_in[6];
  const float* ln2b  = (const float*)d_in[7];
  const float* wfc1  = (const float*)d_in[8];   // [1024][4096]
  const float* bfc1  = (const float*)d_in[9];
  const float* wfc2  = (const float*)d_in[10];  // [4096][1024]
  const float* bfc2  = (const float*)d_in[11];
  float* out = (float*)d_out;

  const size_t MB = 1u << 20;
  if (ws_size < 88 * MB) return;  // layout below needs 88 MB
  char* w = (char*)d_ws;
  unsigned short* xn    = (unsigned short*)(w + 0 * MB);   // 8 MB
  unsigned short* qbuf  = (unsigned short*)(w + 8 * MB);   // 8 MB
  unsigned short* kbuf  = (unsigned short*)(w + 16 * MB);  // 8 MB
  unsigned short* hbuf  = (unsigned short*)(w + 0 * MB);   // 32 MB, aliases xn/q/k (dead by fc1)
  unsigned short* obuf  = (unsigned short*)(w + 32 * MB);  // 8 MB
  float*          x2    = (float*)         (w + 40 * MB);  // 16 MB
  unsigned short* xn2   = (unsigned short*)(w + 56 * MB);  // 8 MB
  unsigned short* vtb   = (unsigned short*)(w + 56 * MB);  // 8 MB, dead before xn2 is written
  unsigned short* wqkvt = (unsigned short*)(w + 64 * MB);  // 6 MB
  unsigned short* wprjt = (unsigned short*)(w + 70 * MB);  // 2 MB
  unsigned short* wfc1t = (unsigned short*)(w + 72 * MB);  // 8 MB
  unsigned short* wfc2t = (unsigned short*)(w + 80 * MB);  // 8 MB

  ln_kernel<<<M_ / 4, 256, 0, stream>>>(x, ln1g, ln1b, xn);
  wtrans_all<<<12288, dim3(32, 8), 0, stream>>>(wqkv, wproj, wfc1, wfc2,
                                                wqkvt, wprjt, wfc1t, wfc2t);

  // QKV (v written directly transposed into vtb; q pre-scaled by 0.125*log2e)
  gemm256_kernel<0><<<dim3(3 * C_ / 256, M_ / 256), 512, 0, stream>>>(
      xn, wqkvt, nullptr, qbuf, kbuf, vtb, M_, 3 * C_, C_);
  attn_kernel<<<B_ * H_ * (N_ / 256), 512, 0, stream>>>(qbuf, kbuf, vtb, obuf);
  // proj: BN=64 dbuf structure, 512 blocks (2/CU), XCD-swizzled
  gemm_db_kernel<<<dim3(C_ / 64, M_ / 128), 256, 0, stream>>>(
      obuf, wprjt, bproj, x, x2, M_, C_, C_);
  ln_kernel<<<M_ / 4, 256, 0, stream>>>(x2, ln2g, ln2b, xn2);
  gemm256_kernel<2><<<dim3(HID_ / 256, M_ / 256), 512, 0, stream>>>(
      xn2, wfc1t, bfc1, hbuf, nullptr, nullptr, M_, HID_, C_);
  // fc2: BN=64 dbuf structure, 512 blocks (2/CU), XCD-swizzled
  gemm_db_kernel<<<dim3(C_ / 64, M_ / 128), 256, 0, stream>>>(
      hbuf, wfc2t, bfc2, x2, out, M_, C_, HID_);
}